// Round 1
// baseline (220.267 us; speedup 1.0000x reference)
//
#include <hip/hip_runtime.h>
#include <math.h>

#define NHID 128
#define TILE_E 128
#define LDK 264   // padded K stride in bf16 elems (256 + 8): even bank spread for b128 reads

typedef __bf16 bf16x8 __attribute__((ext_vector_type(8)));
typedef float f32x4 __attribute__((ext_vector_type(4)));
typedef unsigned short u16x8 __attribute__((ext_vector_type(8)));

__device__ __forceinline__ unsigned short f2bf(float f) {
  unsigned int u = __float_as_uint(f);
  u += 0x7fffu + ((u >> 16) & 1u);   // RNE
  return (unsigned short)(u >> 16);
}

__global__ __launch_bounds__(256, 1)
void mlp_edge_decoder(const float* __restrict__ inputs,
                      const int* __restrict__ x_idx,
                      const int* __restrict__ y_idx,
                      const float* __restrict__ W1,
                      const float* __restrict__ bias1,
                      const float* __restrict__ W2,
                      const float* __restrict__ bias2,
                      float* __restrict__ out,
                      int n_edges)
{
  // LDS: 2*67584 + 2048 = 137216 B -> 1 block/CU (160 KiB available)
  __shared__ __align__(16) unsigned short sW1T[NHID][LDK];   // [n][k] transposed, bf16
  __shared__ __align__(16) unsigned short sA[TILE_E][LDK];   // [edge_row][k] concat(x,y), bf16
  __shared__ float sB1[NHID];
  __shared__ float sW2[NHID];
  __shared__ float sRed[2][TILE_E];

  const int tid  = threadIdx.x;
  const int lane = tid & 63;
  const int wv   = tid >> 6;     // wave 0..3
  const int seg  = tid & 63;     // fixed 16B (4-float) segment of a 256-elem row
  const int m15  = lane & 15;
  const int quad = lane >> 4;
  const int eh   = wv >> 1;      // edge half (64 rows)
  const int ch   = wv & 1;       // col half (64 cols)

  // ---- one-time stage: W1 transposed to bf16, bias1, W2 ----
  for (int i = tid; i < 256 * NHID; i += 256) {
    int k = i >> 7;        // 0..255
    int n = i & 127;       // 0..127
    sW1T[n][k] = f2bf(W1[i]);            // W1 row-major [k][n]
  }
  if (tid < NHID) { sB1[tid] = bias1[tid]; sW2[tid] = W2[tid]; }
  const float b2 = bias2[0];

  const int stride = gridDim.x * TILE_E;
  int ebase = blockIdx.x * TILE_E;

  // register staging: each thread owns segment `seg` of rows wv+4j, j=0..31
  float4 stage[32];
  #pragma unroll
  for (int j = 0; j < 32; ++j) {
    int e  = ebase + 4 * j + wv;
    int ec = (e < n_edges) ? e : 0;
    int idx = (seg < 32) ? x_idx[ec] : y_idx[ec];
    stage[j] = *(const float4*)(inputs + (size_t)idx * NHID + (seg & 31) * 4);
  }

  for (; ebase < n_edges; ebase += stride) {
    // ---- write staged tile to LDS (fp32 -> bf16) ----
    #pragma unroll
    for (int j = 0; j < 32; ++j) {
      int r = wv + 4 * j;
      ushort4 p;
      p.x = f2bf(stage[j].x);
      p.y = f2bf(stage[j].y);
      p.z = f2bf(stage[j].z);
      p.w = f2bf(stage[j].w);
      *(ushort4*)(&sA[r][seg * 4]) = p;
    }
    __syncthreads();

    // ---- issue next tile's gathers now; latency hides under the MFMA loop ----
    {
      int nb = ebase + stride;
      if (nb < n_edges) {
        #pragma unroll
        for (int j = 0; j < 32; ++j) {
          int e  = nb + 4 * j + wv;
          int ec = (e < n_edges) ? e : 0;
          int idx = (seg < 32) ? x_idx[ec] : y_idx[ec];
          stage[j] = *(const float4*)(inputs + (size_t)idx * NHID + (seg & 31) * 4);
        }
      }
    }

    // ---- MFMA: wave computes 64 edges x 64 cols (4x4 tiles of 16x16) ----
    f32x4 acc[4][4];
    #pragma unroll
    for (int mt = 0; mt < 4; ++mt)
      #pragma unroll
      for (int nt = 0; nt < 4; ++nt)
        acc[mt][nt] = (f32x4){0.f, 0.f, 0.f, 0.f};

    #pragma unroll
    for (int ks = 0; ks < 8; ++ks) {
      bf16x8 af[4], bfr[4];
      #pragma unroll
      for (int mt = 0; mt < 4; ++mt)
        af[mt] = __builtin_bit_cast(bf16x8,
                   *(const u16x8*)(&sA[eh * 64 + mt * 16 + m15][ks * 32 + quad * 8]));
      #pragma unroll
      for (int nt = 0; nt < 4; ++nt)
        bfr[nt] = __builtin_bit_cast(bf16x8,
                   *(const u16x8*)(&sW1T[ch * 64 + nt * 16 + m15][ks * 32 + quad * 8]));
      #pragma unroll
      for (int mt = 0; mt < 4; ++mt)
        #pragma unroll
        for (int nt = 0; nt < 4; ++nt)
          acc[mt][nt] = __builtin_amdgcn_mfma_f32_16x16x32_bf16(af[mt], bfr[nt], acc[mt][nt], 0, 0, 0);
    }

    // ---- epilogue: bias1 + relu + dot(W2), reduce 16 lanes, cross-wave via LDS ----
    #pragma unroll
    for (int mt = 0; mt < 4; ++mt) {
      #pragma unroll
      for (int r = 0; r < 4; ++r) {
        float s = 0.f;
        #pragma unroll
        for (int nt = 0; nt < 4; ++nt) {
          int c = ch * 64 + nt * 16 + m15;               // D: col = lane&15
          float h = acc[mt][nt][r] + sB1[c];             // D: row = quad*4 + r
          h = fmaxf(h, 0.f);
          s = fmaf(h, sW2[c], s);
        }
        s += __shfl_xor(s, 1);
        s += __shfl_xor(s, 2);
        s += __shfl_xor(s, 4);
        s += __shfl_xor(s, 8);
        if (m15 == 0) sRed[ch][eh * 64 + mt * 16 + quad * 4 + r] = s;
      }
    }
    __syncthreads();

    // ---- combine col-halves, sigmoid, coalesced store ----
    if (tid < TILE_E) {
      int e = ebase + tid;
      if (e < n_edges) {
        float s = sRed[0][tid] + sRed[1][tid] + b2;
        out[e] = 1.f / (1.f + __expf(-s));
      }
    }
  }
}

extern "C" void kernel_launch(void* const* d_in, const int* in_sizes, int n_in,
                              void* d_out, int out_size, void* d_ws, size_t ws_size,
                              hipStream_t stream) {
  const float* inputs = (const float*)d_in[0];
  const int*   x_idx  = (const int*)d_in[1];
  const int*   y_idx  = (const int*)d_in[2];
  const float* W1     = (const float*)d_in[3];
  const float* bias1  = (const float*)d_in[4];
  const float* W2     = (const float*)d_in[5];
  const float* bias2  = (const float*)d_in[6];
  float* out = (float*)d_out;
  const int n_edges = in_sizes[1];

  // grid 512: 1 block/CU (137 KB LDS), 2 scheduling rounds, ~7.6 tiles/block
  hipLaunchKernelGGL(mlp_edge_decoder, dim3(512), dim3(256), 0, stream,
                     inputs, x_idx, y_idx, W1, bias1, W2, bias2, out, n_edges);
}